// Round 1
// baseline (1275.824 us; speedup 1.0000x reference)
//
#include <hip/hip_runtime.h>
#include <hip/hip_bf16.h>
#include <math.h>

#define B_ 64
#define F_ 128
#define S_ 2048
#define FS_ (F_*S_)   /* 262144 */
#define M_  (B_*F_)   /* 8192 */
#define EPS_ 1e-5f

// ---------------- BatchNorm: per-column stats over batch ----------------
__global__ __launch_bounds__(256) void bn_stats_k(const float* __restrict__ x,
    const float* __restrict__ gamma, const float* __restrict__ beta,
    float* __restrict__ scl, float* __restrict__ shf)
{
  int j4 = blockIdx.x * 256 + threadIdx.x;           // 0 .. FS/4-1
  const float4* x4 = (const float4*)x;
  float sum[4] = {0,0,0,0}, sq[4] = {0,0,0,0};
  for (int b = 0; b < B_; b++) {
    float4 v = x4[(size_t)b * (FS_/4) + j4];
    float vv[4] = {v.x, v.y, v.z, v.w};
    #pragma unroll
    for (int i = 0; i < 4; i++) { sum[i] += vv[i]; sq[i] += vv[i]*vv[i]; }
  }
  #pragma unroll
  for (int i = 0; i < 4; i++) {
    int j = j4*4 + i;
    float mu  = sum[i] * (1.0f/B_);
    float var = sq[i] * (1.0f/B_) - mu*mu;
    float rstd = rsqrtf(var + EPS_);
    float g = gamma[j];
    scl[j] = rstd * g;
    shf[j] = beta[j] - mu * rstd * g;
  }
}

// ---------------- BatchNorm apply: xn -> d_out ----------------
__global__ __launch_bounds__(256) void bn_apply_k(const float* __restrict__ x,
    const float* __restrict__ scl, const float* __restrict__ shf,
    float* __restrict__ out)
{
  int idx4 = blockIdx.x * 256 + threadIdx.x;         // over B*FS/4
  int j4 = idx4 & (FS_/4 - 1);
  float4 v = ((const float4*)x)[idx4];
  float4 sc = ((const float4*)scl)[j4];
  float4 sh = ((const float4*)shf)[j4];
  float4 o;
  o.x = fmaf(v.x, sc.x, sh.x);
  o.y = fmaf(v.y, sc.y, sh.y);
  o.z = fmaf(v.z, sc.z, sh.z);
  o.w = fmaf(v.w, sc.w, sh.w);
  ((float4*)out)[idx4] = o;
}

// ---------------- Pool: avg/max over k, plus per-(b,f) row stats ----------------
__global__ __launch_bounds__(256) void pool_k(const float* __restrict__ xn,
    float* __restrict__ avg, float* __restrict__ mx, float* __restrict__ stats,
    int k, int L)
{
  int bf = blockIdx.x;                                // 0..M_-1 ; row offset bf*S_
  int tid = threadIdx.x;
  const float* row = xn + (size_t)bf * S_;
  float lsum = 0.0f, lsq = 0.0f, lmax = -INFINITY;
  for (int g = tid; g < L; g += 256) {
    const float* p = row + g*k;
    float a = p[0], m = p[0];
    for (int i = 1; i < k; i++) { float v = p[i]; a += v; m = fmaxf(m, v); }
    a *= (1.0f/(float)k);
    avg[(size_t)bf*L + g] = a;
    mx [(size_t)bf*L + g] = m;
    float pf = 0.5f*(a + m);
    lsum += pf; lsq += pf*pf; lmax = fmaxf(lmax, pf);
  }
  __shared__ float rs[256], rq[256], rm[256];
  rs[tid] = lsum; rq[tid] = lsq; rm[tid] = lmax;
  __syncthreads();
  for (int s = 128; s > 0; s >>= 1) {
    if (tid < s) {
      rs[tid] += rs[tid+s];
      rq[tid] += rq[tid+s];
      rm[tid] = fmaxf(rm[tid], rm[tid+s]);
    }
    __syncthreads();
  }
  if (tid == 0) {
    float mean = rs[0] / (float)L;
    float var  = (rq[0] - rs[0]*rs[0]/(float)L) / (float)(L - 1);  // ddof=1
    float sd = sqrtf(fmaxf(var, 0.0f));
    int b = bf / F_, f = bf % F_;
    stats[b*384 + f]       = mean;
    stats[b*384 + 128 + f] = sd;
    stats[b*384 + 256 + f] = rm[0];
  }
}

// ---------------- Selector MLP: w[b] = sigmoid(relu(stats@w1+b1)@w2+b2) ----------------
__global__ __launch_bounds__(64) void sel_k(const float* __restrict__ stats,
    const float* __restrict__ w1, const float* __restrict__ b1,
    const float* __restrict__ w2, const float* __restrict__ b2,
    float* __restrict__ wout)
{
  int b = blockIdx.x, j = threadIdx.x;                // 64 threads = 1 wave
  const float* st = stats + b*384;
  float acc = b1[j];
  for (int i = 0; i < 384; i++) acc = fmaf(st[i], w1[i*64 + j], acc);
  float h = fmaxf(acc, 0.0f);
  float v = h * w2[j];
  for (int off = 32; off > 0; off >>= 1) v += __shfl_down(v, off);
  if (j == 0) wout[b] = 1.0f / (1.0f + expf(-(v + b2[0])));
}

// ---------------- Combine: samp = w*avg + (1-w)*mx   (in-place over avg) ----------------
__global__ __launch_bounds__(256) void comb_k(float* __restrict__ samp,
    const float* __restrict__ mx, const float* __restrict__ wsel, int FL)
{
  int idx4 = blockIdx.x * 256 + threadIdx.x;          // over M*L/4
  int b = (idx4 * 4) / FL;                            // FL multiple of 4 -> uniform b
  float w = wsel[b], u = 1.0f - w;
  float4 a = ((const float4*)samp)[idx4];
  float4 m = ((const float4*)mx  )[idx4];
  float4 o;
  o.x = w*a.x + u*m.x; o.y = w*a.y + u*m.y;
  o.z = w*a.z + u*m.z; o.w = w*a.w + u*m.w;
  ((float4*)samp)[idx4] = o;
}

// ---------------- Tiled fp32 GEMM: C = [gelu](A@W + bias) [+ C_old] ----------------
__device__ __forceinline__ float gelu_exact(float x) {
  return 0.5f * x * (1.0f + erff(x * 0.70710678118654752f));
}

template<bool GELU, bool ACC>
__global__ __launch_bounds__(256) void sgemm_k(const float* __restrict__ A,
    const float* __restrict__ W, const float* __restrict__ bias,
    float* __restrict__ C, int M, int N, int K)
{
  __shared__ float As[8][128];   // [k][m]  (A tile stored transposed)
  __shared__ float Bs[8][128];   // [k][n]
  const int tid = threadIdx.x;
  const int bm = blockIdx.y * 128;
  const int bn = blockIdx.x * 128;
  const int arow = tid >> 1;            // 0..127
  const int akk  = (tid & 1) * 4;       // 0 or 4
  const int wkk  = tid >> 5;            // 0..7
  const int wcol = (tid & 31) * 4;      // 0..124
  const int tx = tid & 15;              // n-group
  const int ty = tid >> 4;              // m-group

  float acc[8][8];
  #pragma unroll
  for (int i = 0; i < 8; i++)
    #pragma unroll
    for (int j = 0; j < 8; j++) acc[i][j] = 0.0f;

  const float* Ap = A + (size_t)(bm + arow) * K + akk;
  const float* Wp = W + (size_t)wkk * N + bn + wcol;

  for (int k0 = 0; k0 < K; k0 += 8) {
    float4 av = *(const float4*)(Ap + k0);
    float4 wv = *(const float4*)(Wp + (size_t)k0 * N);
    __syncthreads();   // previous tile's compute done before overwrite
    As[akk+0][arow] = av.x;
    As[akk+1][arow] = av.y;
    As[akk+2][arow] = av.z;
    As[akk+3][arow] = av.w;
    *(float4*)&Bs[wkk][wcol] = wv;
    __syncthreads();
    #pragma unroll
    for (int kk = 0; kk < 8; kk++) {
      float4 a0 = *(const float4*)&As[kk][ty*4];
      float4 a1 = *(const float4*)&As[kk][64 + ty*4];
      float4 b0 = *(const float4*)&Bs[kk][tx*4];
      float4 b1 = *(const float4*)&Bs[kk][64 + tx*4];
      float af[8] = {a0.x,a0.y,a0.z,a0.w, a1.x,a1.y,a1.z,a1.w};
      float bf[8] = {b0.x,b0.y,b0.z,b0.w, b1.x,b1.y,b1.z,b1.w};
      #pragma unroll
      for (int i = 0; i < 8; i++)
        #pragma unroll
        for (int j = 0; j < 8; j++)
          acc[i][j] = fmaf(af[i], bf[j], acc[i][j]);
    }
  }

  #pragma unroll
  for (int i = 0; i < 8; i++) {
    int r = bm + ((i < 4) ? (ty*4 + i) : (64 + ty*4 + i - 4));
    #pragma unroll
    for (int jh = 0; jh < 2; jh++) {
      int c = bn + jh*64 + tx*4;
      float v[4];
      #pragma unroll
      for (int q = 0; q < 4; q++) {
        float t = acc[i][jh*4 + q] + bias[c + q];
        if (GELU) t = gelu_exact(t);
        v[q] = t;
      }
      float* cp = C + (size_t)r * N + c;
      if (ACC) {
        float4 old = *(const float4*)cp;
        v[0] += old.x; v[1] += old.y; v[2] += old.z; v[3] += old.w;
      }
      float4 o = {v[0], v[1], v[2], v[3]};
      *(float4*)cp = o;
    }
  }
}

// ---------------- launch ----------------
extern "C" void kernel_launch(void* const* d_in, const int* in_sizes, int n_in,
                              void* d_out, int out_size, void* d_ws, size_t ws_size,
                              hipStream_t stream)
{
  const float* x     = (const float*)d_in[0];
  const float* gamma = (const float*)d_in[1];
  const float* beta  = (const float*)d_in[2];
  float* out = (float*)d_out;
  float* ws  = (float*)d_ws;

  size_t off = 0;
  float* samp[3];
  samp[0] = ws + off; off += (size_t)M_ * 256;    // 8 MB
  samp[1] = ws + off; off += (size_t)M_ * 512;    // 16 MB
  samp[2] = ws + off; off += (size_t)M_ * 1024;   // 32 MB
  float* scratch = ws + off; off += (size_t)M_ * 1024;  // 32 MB (mx, then h)
  float* scl   = ws + off; off += FS_;
  float* shf   = ws + off; off += FS_;
  float* stats = ws + off; off += 64 * 384;
  float* wsel  = ws + off; off += 64;

  // 1) BatchNorm
  bn_stats_k<<<FS_/4/256, 256, 0, stream>>>(x, gamma, beta, scl, shf);
  bn_apply_k<<<(B_*(FS_/4))/256, 256, 0, stream>>>(x, scl, shf, out);  // out = xn = samples[3]

  static const int KS[3] = {8, 4, 2};

  // 2) Pooling + selector + combine per scale
  for (int s = 0; s < 3; s++) {
    int k = KS[s], L = S_ / k;
    const float* sw1 = (const float*)d_in[3 + 8*s + 0];
    const float* sb1 = (const float*)d_in[3 + 8*s + 1];
    const float* sw2 = (const float*)d_in[3 + 8*s + 2];
    const float* sb2 = (const float*)d_in[3 + 8*s + 3];
    pool_k<<<M_, 256, 0, stream>>>(out, samp[s], scratch, stats, k, L);
    sel_k<<<B_, 64, 0, stream>>>(stats, sw1, sb1, sw2, sb2, wsel);
    comb_k<<<(M_*L/4)/256, 256, 0, stream>>>(samp[s], scratch, wsel, F_*L);
  }

  // 3) Linear chain: h = gelu(samp[s]@lw1+lb1); next += h@lw2+lb2
  for (int s = 0; s < 3; s++) {
    int L = S_ / KS[s];
    const float* lw1 = (const float*)d_in[3 + 8*s + 4];
    const float* lb1 = (const float*)d_in[3 + 8*s + 5];
    const float* lw2 = (const float*)d_in[3 + 8*s + 6];
    const float* lb2 = (const float*)d_in[3 + 8*s + 7];
    sgemm_k<true, false><<<dim3(L/128, M_/128), 256, 0, stream>>>(
        samp[s], lw1, lb1, scratch, M_, L, L);
    float* tgt = (s < 2) ? samp[s+1] : out;
    sgemm_k<false, true><<<dim3(2*L/128, M_/128), 256, 0, stream>>>(
        scratch, lw2, lb2, tgt, M_, 2*L, L);
  }
}

// Round 2
// 555.124 us; speedup vs baseline: 2.2983x; 2.2983x over previous
//
#include <hip/hip_runtime.h>
#include <hip/hip_bf16.h>
#include <math.h>

#define B_ 64
#define F_ 128
#define S_ 2048
#define FS_ (F_*S_)   /* 262144 */
#define M_  (B_*F_)   /* 8192 */
#define EPS_ 1e-5f

typedef __bf16 v8bf __attribute__((ext_vector_type(8)));
typedef float  v4f  __attribute__((ext_vector_type(4)));

__device__ __forceinline__ unsigned short f2bf_rne(float f) {
  unsigned int u = __float_as_uint(f);
  u += 0x7FFF + ((u >> 16) & 1);
  return (unsigned short)(u >> 16);
}

__device__ __forceinline__ float gelu_exact(float x) {
  return 0.5f * x * (1.0f + erff(x * 0.70710678118654752f));
}

// async global->LDS, 16B per lane, lds base must be wave-uniform
#define GLDS16(g, l) __builtin_amdgcn_global_load_lds( \
    (const __attribute__((address_space(1))) unsigned int*)(g), \
    (__attribute__((address_space(3))) unsigned int*)(l), 16, 0, 0)

// ---------------- BatchNorm: per-column stats over batch ----------------
__global__ __launch_bounds__(256) void bn_stats_k(const float* __restrict__ x,
    const float* __restrict__ gamma, const float* __restrict__ beta,
    float* __restrict__ scl, float* __restrict__ shf)
{
  int j4 = blockIdx.x * 256 + threadIdx.x;
  const float4* x4 = (const float4*)x;
  float sum[4] = {0,0,0,0}, sq[4] = {0,0,0,0};
  for (int b = 0; b < B_; b++) {
    float4 v = x4[(size_t)b * (FS_/4) + j4];
    float vv[4] = {v.x, v.y, v.z, v.w};
    #pragma unroll
    for (int i = 0; i < 4; i++) { sum[i] += vv[i]; sq[i] += vv[i]*vv[i]; }
  }
  #pragma unroll
  for (int i = 0; i < 4; i++) {
    int j = j4*4 + i;
    float mu  = sum[i] * (1.0f/B_);
    float var = sq[i] * (1.0f/B_) - mu*mu;
    float rstd = rsqrtf(var + EPS_);
    float g = gamma[j];
    scl[j] = rstd * g;
    shf[j] = beta[j] - mu * rstd * g;
  }
}

__global__ __launch_bounds__(256) void bn_apply_k(const float* __restrict__ x,
    const float* __restrict__ scl, const float* __restrict__ shf,
    float* __restrict__ out)
{
  int idx4 = blockIdx.x * 256 + threadIdx.x;
  int j4 = idx4 & (FS_/4 - 1);
  float4 v = ((const float4*)x)[idx4];
  float4 sc = ((const float4*)scl)[j4];
  float4 sh = ((const float4*)shf)[j4];
  float4 o;
  o.x = fmaf(v.x, sc.x, sh.x);
  o.y = fmaf(v.y, sc.y, sh.y);
  o.z = fmaf(v.z, sc.z, sh.z);
  o.w = fmaf(v.w, sc.w, sh.w);
  ((float4*)out)[idx4] = o;
}

// ---------------- Pool + per-(b,f) row stats ----------------
__global__ __launch_bounds__(256) void pool_k(const float* __restrict__ xn,
    float* __restrict__ avg, float* __restrict__ mx, float* __restrict__ stats,
    int k, int L)
{
  int bf = blockIdx.x;
  int tid = threadIdx.x;
  const float* row = xn + (size_t)bf * S_;
  float lsum = 0.0f, lsq = 0.0f, lmax = -INFINITY;
  for (int g = tid; g < L; g += 256) {
    const float* p = row + g*k;
    float a = p[0], m = p[0];
    for (int i = 1; i < k; i++) { float v = p[i]; a += v; m = fmaxf(m, v); }
    a *= (1.0f/(float)k);
    avg[(size_t)bf*L + g] = a;
    mx [(size_t)bf*L + g] = m;
    float pf = 0.5f*(a + m);
    lsum += pf; lsq += pf*pf; lmax = fmaxf(lmax, pf);
  }
  __shared__ float rs[256], rq[256], rm[256];
  rs[tid] = lsum; rq[tid] = lsq; rm[tid] = lmax;
  __syncthreads();
  for (int s = 128; s > 0; s >>= 1) {
    if (tid < s) {
      rs[tid] += rs[tid+s];
      rq[tid] += rq[tid+s];
      rm[tid] = fmaxf(rm[tid], rm[tid+s]);
    }
    __syncthreads();
  }
  if (tid == 0) {
    float mean = rs[0] / (float)L;
    float var  = (rq[0] - rs[0]*rs[0]/(float)L) / (float)(L - 1);
    float sd = sqrtf(fmaxf(var, 0.0f));
    int b = bf / F_, f = bf % F_;
    stats[b*384 + f]       = mean;
    stats[b*384 + 128 + f] = sd;
    stats[b*384 + 256 + f] = rm[0];
  }
}

// ---------------- Selector MLP ----------------
__global__ __launch_bounds__(64) void sel_k(const float* __restrict__ stats,
    const float* __restrict__ w1, const float* __restrict__ b1,
    const float* __restrict__ w2, const float* __restrict__ b2,
    float* __restrict__ wout)
{
  int b = blockIdx.x, j = threadIdx.x;
  const float* st = stats + b*384;
  float acc = b1[j];
  for (int i = 0; i < 384; i++) acc = fmaf(st[i], w1[i*64 + j], acc);
  float h = fmaxf(acc, 0.0f);
  float v = h * w2[j];
  for (int off = 32; off > 0; off >>= 1) v += __shfl_down(v, off);
  if (j == 0) wout[b] = 1.0f / (1.0f + expf(-(v + b2[0])));
}

// ---------------- Combine: samp = w*avg + (1-w)*mx ----------------
// TOBF: write bf16 to obf; else write fp32 in place over avg buffer
template<bool TOBF>
__global__ __launch_bounds__(256) void comb_k(float* __restrict__ a_in,
    const float* __restrict__ mx, const float* __restrict__ wsel, int FL,
    unsigned short* __restrict__ obf)
{
  int idx4 = blockIdx.x * 256 + threadIdx.x;
  int b = (idx4 * 4) / FL;
  float w = wsel[b], u = 1.0f - w;
  float4 a = ((const float4*)a_in)[idx4];
  float4 m = ((const float4*)mx  )[idx4];
  float4 o;
  o.x = w*a.x + u*m.x; o.y = w*a.y + u*m.y;
  o.z = w*a.z + u*m.z; o.w = w*a.w + u*m.w;
  if (TOBF) {
    ushort4 s;
    s.x = f2bf_rne(o.x); s.y = f2bf_rne(o.y);
    s.z = f2bf_rne(o.z); s.w = f2bf_rne(o.w);
    ((ushort4*)obf)[idx4] = s;
  } else {
    ((float4*)a_in)[idx4] = o;
  }
}

// ---------------- Weight transpose + cvt: W[K][N] f32 -> Wt[N][K] bf16 ----------------
__global__ __launch_bounds__(256) void wt_cvt_k(const float* __restrict__ W,
    unsigned short* __restrict__ Wt, int K, int N)
{
  __shared__ float tile[32][33];
  int k0 = blockIdx.y * 32, n0 = blockIdx.x * 32;
  int tx = threadIdx.x & 31, ty = threadIdx.x >> 5;   // ty 0..7
  #pragma unroll
  for (int i = ty; i < 32; i += 8)
    tile[i][tx] = W[(size_t)(k0 + i) * N + n0 + tx];
  __syncthreads();
  #pragma unroll
  for (int i = ty; i < 32; i += 8)
    Wt[(size_t)(n0 + i) * K + k0 + tx] = f2bf_rne(tile[tx][i]);
}

// ---------------- bf16 MFMA GEMM: C = op(A@W + bias) ----------------
// A: [M][K] bf16 ; Wt: [N][K] bf16 (W transposed)
// MODE 0: gelu -> bf16 Obf
// MODE 1: + Cold(f32) -> bf16 Obf
// MODE 2: + Cold(f32) -> f32 Of32
template<int MODE>
__global__ __launch_bounds__(256) void mgemm_k(
    const unsigned short* __restrict__ A,
    const unsigned short* __restrict__ Wt,
    const float* __restrict__ bias,
    const float* __restrict__ Cold,
    unsigned short* __restrict__ Obf,
    float* __restrict__ Of32,
    int K, int N)
{
  __shared__ v8bf As8[128*4];   // [m][k-chunk], 64B rows -> 8 KB
  __shared__ v8bf Bs8[128*4];   // [n][k-chunk]
  const int tid  = threadIdx.x;
  const int lane = tid & 63;
  const int w    = tid >> 6;               // wave 0..3
  const int bm   = blockIdx.y * 128;
  const int bn   = blockIdx.x * 128;
  const int wm   = (w >> 1) * 64;          // wave's 64x64 subtile
  const int wn   = (w & 1) * 64;

  v4f acc[4][4];
  #pragma unroll
  for (int i = 0; i < 4; i++)
    #pragma unroll
    for (int j = 0; j < 4; j++)
      acc[i][j] = (v4f){0.f, 0.f, 0.f, 0.f};

  // staging: wave w covers rows [w*32, w*32+32), 2 calls of 16 rows each,
  // lane i -> row +i/4, 16B chunk (i%4)
  const unsigned short* ag = A  + (size_t)(bm + w*32 + (lane >> 2)) * K + (lane & 3) * 8;
  const unsigned short* bg = Wt + (size_t)(bn + w*32 + (lane >> 2)) * K + (lane & 3) * 8;
  char* al = (char*)As8 + w*32*64;
  char* bl = (char*)Bs8 + w*32*64;
  const size_t row16 = (size_t)16 * K;     // 16 rows of bf16 elements

  for (int k0 = 0; k0 < K; k0 += 32) {
    __syncthreads();                        // previous tile's compute done
    GLDS16(ag + k0,          al);
    GLDS16(ag + row16 + k0,  al + 16*64);
    GLDS16(bg + k0,          bl);
    GLDS16(bg + row16 + k0,  bl + 16*64);
    __syncthreads();                        // drains vmcnt: data visible

    v8bf af[4], bf[4];
    #pragma unroll
    for (int t = 0; t < 4; t++) {
      af[t] = As8[(wm + t*16 + (lane & 15)) * 4 + (lane >> 4)];
      bf[t] = Bs8[(wn + t*16 + (lane & 15)) * 4 + (lane >> 4)];
    }
    #pragma unroll
    for (int i = 0; i < 4; i++)
      #pragma unroll
      for (int j = 0; j < 4; j++)
        acc[i][j] = __builtin_amdgcn_mfma_f32_16x16x32_bf16(af[i], bf[j], acc[i][j], 0, 0, 0);
  }

  // epilogue: C/D layout col=lane&15, row=(lane>>4)*4+reg
  const int col0 = bn + wn + (lane & 15);
  const int row0 = bm + wm + ((lane >> 4) << 2);
  #pragma unroll
  for (int j = 0; j < 4; j++) {
    int c = col0 + j*16;
    float bv = bias[c];
    #pragma unroll
    for (int i = 0; i < 4; i++) {
      #pragma unroll
      for (int r = 0; r < 4; r++) {
        int rr = row0 + i*16 + r;
        size_t idx = (size_t)rr * N + c;
        float t = acc[i][j][r] + bv;
        if (MODE == 0) {
          Obf[idx] = f2bf_rne(gelu_exact(t));
        } else if (MODE == 1) {
          Obf[idx] = f2bf_rne(t + Cold[idx]);
        } else {
          Of32[idx] = t + Cold[idx];
        }
      }
    }
  }
}

// ---------------- launch ----------------
extern "C" void kernel_launch(void* const* d_in, const int* in_sizes, int n_in,
                              void* d_out, int out_size, void* d_ws, size_t ws_size,
                              hipStream_t stream)
{
  const float* x     = (const float*)d_in[0];
  const float* gamma = (const float*)d_in[1];
  const float* beta  = (const float*)d_in[2];
  float* out = (float*)d_out;
  float* ws  = (float*)d_ws;

  static const int KS[3] = {8, 4, 2};

  // ---- workspace layout (float units) ----
  size_t off = 0;
  float* samp1 = ws + off; off += (size_t)M_ * 512;    // 16 MB fp32
  float* samp2 = ws + off; off += (size_t)M_ * 1024;   // 32 MB fp32
  float* avg0  = ws + off; off += (size_t)M_ * 256;    //  8 MB fp32
  float* mxbuf = ws + off; off += (size_t)M_ * 1024;   // 32 MB fp32; reused as hb
  float* scl   = ws + off; off += FS_;
  float* shf   = ws + off; off += FS_;
  float* stats = ws + off; off += 64 * 384;
  float* wsel  = ws + off; off += 64;
  // bf16 region (2 ushort per float slot)
  unsigned short* sampb[3];
  sampb[0] = (unsigned short*)(ws + off); off += (size_t)M_ * 256 / 2;
  sampb[1] = (unsigned short*)(ws + off); off += (size_t)M_ * 512 / 2;
  sampb[2] = (unsigned short*)(ws + off); off += (size_t)M_ * 1024 / 2;
  unsigned short* wt1[3], *wt2[3];
  for (int s = 0; s < 3; s++) {
    int L = S_ / KS[s];
    wt1[s] = (unsigned short*)(ws + off); off += (size_t)L * L / 2;
    wt2[s] = (unsigned short*)(ws + off); off += (size_t)L * 2 * L / 2;
  }
  unsigned short* hb = (unsigned short*)mxbuf;  // alias: mx dead before GEMM phase

  // ---- weight cvt+transpose (independent of everything else) ----
  for (int s = 0; s < 3; s++) {
    int L = S_ / KS[s];
    const float* lw1 = (const float*)d_in[3 + 8*s + 4];
    const float* lw2 = (const float*)d_in[3 + 8*s + 6];
    wt_cvt_k<<<dim3(L/32, L/32), 256, 0, stream>>>(lw1, wt1[s], L, L);
    wt_cvt_k<<<dim3(2*L/32, L/32), 256, 0, stream>>>(lw2, wt2[s], L, 2*L);
  }

  // ---- BatchNorm: out = xn ----
  bn_stats_k<<<FS_/4/256, 256, 0, stream>>>(x, gamma, beta, scl, shf);
  bn_apply_k<<<(B_*(FS_/4))/256, 256, 0, stream>>>(x, scl, shf, out);

  // ---- pooling + selector + combine ----
  float* avgb[3] = {avg0, samp1, samp2};
  for (int s = 0; s < 3; s++) {
    int k = KS[s], L = S_ / k;
    const float* sw1 = (const float*)d_in[3 + 8*s + 0];
    const float* sb1 = (const float*)d_in[3 + 8*s + 1];
    const float* sw2 = (const float*)d_in[3 + 8*s + 2];
    const float* sb2 = (const float*)d_in[3 + 8*s + 3];
    pool_k<<<M_, 256, 0, stream>>>(out, avgb[s], mxbuf, stats, k, L);
    sel_k<<<B_, 64, 0, stream>>>(stats, sw1, sb1, sw2, sb2, wsel);
    if (s == 0)
      comb_k<true ><<<(M_*L/4)/256, 256, 0, stream>>>(avgb[s], mxbuf, wsel, F_*L, sampb[0]);
    else
      comb_k<false><<<(M_*L/4)/256, 256, 0, stream>>>(avgb[s], mxbuf, wsel, F_*L, nullptr);
  }

  // ---- GEMM chain (bf16 MFMA) ----
  for (int s = 0; s < 3; s++) {
    int L = S_ / KS[s];
    const float* lb1 = (const float*)d_in[3 + 8*s + 5];
    const float* lb2 = (const float*)d_in[3 + 8*s + 7];
    // h = gelu(samp[s] @ lw1 + lb1)  -> bf16
    mgemm_k<0><<<dim3(L/128, M_/128), 256, 0, stream>>>(
        sampb[s], wt1[s], lb1, nullptr, hb, nullptr, L, L);
    if (s < 2) {
      // samp[s+1] += h @ lw2 + lb2  -> bf16 (A of next stage)
      mgemm_k<1><<<dim3(2*L/128, M_/128), 256, 0, stream>>>(
          hb, wt2[s], lb2, (s == 0) ? samp1 : samp2, sampb[s+1], nullptr, L, 2*L);
    } else {
      // out = xn + h @ lw2 + lb2  -> fp32
      mgemm_k<2><<<dim3(2*L/128, M_/128), 256, 0, stream>>>(
          hb, wt2[s], lb2, out, nullptr, out, L, 2*L);
    }
  }
}

// Round 3
// 412.797 us; speedup vs baseline: 3.0907x; 1.3448x over previous
//
#include <hip/hip_runtime.h>
#include <hip/hip_bf16.h>
#include <math.h>

#define B_ 64
#define F_ 128
#define S_ 2048
#define FS_ (F_*S_)   /* 262144 */
#define M_  (B_*F_)   /* 8192 */
#define EPS_ 1e-5f

typedef __bf16 v8bf __attribute__((ext_vector_type(8)));
typedef float  v4f  __attribute__((ext_vector_type(4)));

__device__ __forceinline__ unsigned short f2bf_rne(float f) {
  unsigned int u = __float_as_uint(f);
  u += 0x7FFF + ((u >> 16) & 1);
  return (unsigned short)(u >> 16);
}

__device__ __forceinline__ float gelu_exact(float x) {
  return 0.5f * x * (1.0f + erff(x * 0.70710678118654752f));
}

// async global->LDS, 16B per lane, lds base wave-uniform, lane lands at +lane*16
#define GLDS16(g, l) __builtin_amdgcn_global_load_lds( \
    (const __attribute__((address_space(1))) unsigned int*)(g), \
    (__attribute__((address_space(3))) unsigned int*)(l), 16, 0, 0)

// ---------------- BatchNorm column stats over batch ----------------
__global__ __launch_bounds__(256) void bn_stats_k(const float* __restrict__ x,
    const float* __restrict__ gamma, const float* __restrict__ beta,
    float* __restrict__ scl, float* __restrict__ shf)
{
  int j4 = blockIdx.x * 256 + threadIdx.x;
  const float4* x4 = (const float4*)x;
  float sum[4] = {0,0,0,0}, sq[4] = {0,0,0,0};
  for (int b = 0; b < B_; b++) {
    float4 v = x4[(size_t)b * (FS_/4) + j4];
    float vv[4] = {v.x, v.y, v.z, v.w};
    #pragma unroll
    for (int i = 0; i < 4; i++) { sum[i] += vv[i]; sq[i] += vv[i]*vv[i]; }
  }
  #pragma unroll
  for (int i = 0; i < 4; i++) {
    int j = j4*4 + i;
    float mu  = sum[i] * (1.0f/B_);
    float var = sq[i] * (1.0f/B_) - mu*mu;
    float rstd = rsqrtf(var + EPS_);
    float g = gamma[j];
    scl[j] = rstd * g;
    shf[j] = beta[j] - mu * rstd * g;
  }
}

// ---------------- Fused BN-apply + hierarchical pool stats ----------------
// thread t owns row elements 8t..8t+7 -> entire k=2/4/8 pool tree is thread-local.
// writes xn to out; writes 9 row-stats (3 scales x mean/sd/max) to stats[3][64*384].
__global__ __launch_bounds__(256) void bnpool_k(const float* __restrict__ x,
    const float* __restrict__ scl, const float* __restrict__ shf,
    float* __restrict__ out, float* __restrict__ stats)
{
  int bf = blockIdx.x, t = threadIdx.x;
  int b = bf >> 7, f = bf & 127;
  const float4* xp  = (const float4*)(x   + (size_t)bf * S_);
  const float4* scp = (const float4*)(scl + (size_t)f  * S_);
  const float4* shp = (const float4*)(shf + (size_t)f  * S_);
  float4* op = (float4*)(out + (size_t)bf * S_);

  float xr[8];
  #pragma unroll
  for (int h = 0; h < 2; h++) {
    int i4 = t*2 + h;
    float4 v = xp[i4], sc = scp[i4], sh = shp[i4];
    float4 o;
    o.x = fmaf(v.x, sc.x, sh.x);
    o.y = fmaf(v.y, sc.y, sh.y);
    o.z = fmaf(v.z, sc.z, sh.z);
    o.w = fmaf(v.w, sc.w, sh.w);
    op[i4] = o;
    xr[h*4+0] = o.x; xr[h*4+1] = o.y; xr[h*4+2] = o.z; xr[h*4+3] = o.w;
  }

  // level 2 (k=2, L=1024, scale s=2): 4 thread-local groups
  float a2[4], m2[4];
  float ps2 = 0.f, pq2 = 0.f, pm2 = -INFINITY;
  #pragma unroll
  for (int j = 0; j < 4; j++) {
    a2[j] = xr[2*j] + xr[2*j+1];
    m2[j] = fmaxf(xr[2*j], xr[2*j+1]);
    float pf = 0.5f * (0.5f * a2[j] + m2[j]);
    ps2 += pf; pq2 += pf*pf; pm2 = fmaxf(pm2, pf);
  }
  // level 4 (k=4, L=512, scale s=1): 2 groups
  float a4[2], m4[2];
  float ps1 = 0.f, pq1 = 0.f, pm1 = -INFINITY;
  #pragma unroll
  for (int j = 0; j < 2; j++) {
    a4[j] = a2[2*j] + a2[2*j+1];
    m4[j] = fmaxf(m2[2*j], m2[2*j+1]);
    float pf = 0.5f * (0.25f * a4[j] + m4[j]);
    ps1 += pf; pq1 += pf*pf; pm1 = fmaxf(pm1, pf);
  }
  // level 8 (k=8, L=256, scale s=0): 1 group
  float a8 = a4[0] + a4[1];
  float m8 = fmaxf(m4[0], m4[1]);
  float pf8 = 0.5f * (0.125f * a8 + m8);
  float ps0 = pf8, pq0 = pf8*pf8, pm0 = pf8;

  __shared__ float wred[12];
  int lane = t & 63, wid = t >> 6;
  float PS[3] = {ps0, ps1, ps2}, PQ[3] = {pq0, pq1, pq2}, PM[3] = {pm0, pm1, pm2};
  int   LL[3] = {256, 512, 1024};
  #pragma unroll
  for (int s = 0; s < 3; s++) {
    float vs = PS[s], vq = PQ[s], vm = PM[s];
    #pragma unroll
    for (int off = 32; off > 0; off >>= 1) {
      vs += __shfl_down(vs, off);
      vq += __shfl_down(vq, off);
      vm = fmaxf(vm, __shfl_down(vm, off));
    }
    if (lane == 0) { wred[wid*3+0] = vs; wred[wid*3+1] = vq; wred[wid*3+2] = vm; }
    __syncthreads();
    if (t == 0) {
      float S = 0.f, Q = 0.f, Mx = -INFINITY;
      #pragma unroll
      for (int i = 0; i < 4; i++) {
        S += wred[i*3+0]; Q += wred[i*3+1]; Mx = fmaxf(Mx, wred[i*3+2]);
      }
      float L = (float)LL[s];
      float mean = S / L;
      float var  = (Q - S*S/L) / (L - 1.0f);
      float* base = stats + s*(64*384) + b*384;
      base[f]       = mean;
      base[128 + f] = sqrtf(fmaxf(var, 0.0f));
      base[256 + f] = Mx;
    }
    __syncthreads();
  }
}

// ---------------- All three selector MLPs in one launch ----------------
__global__ __launch_bounds__(64) void selall_k(const float* __restrict__ stats,
    const float* w1_0, const float* b1_0, const float* w2_0, const float* b2_0,
    const float* w1_1, const float* b1_1, const float* w2_1, const float* b2_1,
    const float* w1_2, const float* b1_2, const float* w2_2, const float* b2_2,
    float* __restrict__ wsel)
{
  int s = blockIdx.y, b = blockIdx.x, j = threadIdx.x;
  const float *w1, *b1, *w2, *b2;
  if      (s == 0) { w1 = w1_0; b1 = b1_0; w2 = w2_0; b2 = b2_0; }
  else if (s == 1) { w1 = w1_1; b1 = b1_1; w2 = w2_1; b2 = b2_1; }
  else             { w1 = w1_2; b1 = b1_2; w2 = w2_2; b2 = b2_2; }
  const float* st = stats + s*(64*384) + b*384;
  float acc = b1[j];
  for (int i = 0; i < 384; i++) acc = fmaf(st[i], w1[i*64 + j], acc);
  float h = fmaxf(acc, 0.0f);
  float v = h * w2[j];
  for (int off = 32; off > 0; off >>= 1) v += __shfl_down(v, off);
  if (j == 0) wsel[s*64 + b] = 1.0f / (1.0f + expf(-(v + b2[0])));
}

// ---------------- Fused pool-recompute + combine -> bf16 A matrices ----------------
__global__ __launch_bounds__(256) void combfused_k(const float* __restrict__ xn,
    const float* __restrict__ wsel,
    unsigned short* __restrict__ o8, unsigned short* __restrict__ o4,
    unsigned short* __restrict__ o2)
{
  int bf = blockIdx.x, t = threadIdx.x, b = bf >> 7;
  float wA = wsel[b];            // k=8 (s=0)
  float wB = wsel[64 + b];       // k=4 (s=1)
  float wC = wsel[128 + b];      // k=2 (s=2)
  const float4* xp = (const float4*)(xn + (size_t)bf * S_);
  float xr[8];
  #pragma unroll
  for (int h = 0; h < 2; h++) {
    float4 v = xp[t*2 + h];
    xr[h*4+0] = v.x; xr[h*4+1] = v.y; xr[h*4+2] = v.z; xr[h*4+3] = v.w;
  }
  float a2[4], m2[4];
  ushort4 u4o;
  unsigned short uu[4];
  #pragma unroll
  for (int j = 0; j < 4; j++) {
    a2[j] = xr[2*j] + xr[2*j+1];
    m2[j] = fmaxf(xr[2*j], xr[2*j+1]);
    uu[j] = f2bf_rne(wC * (0.5f * a2[j]) + (1.0f - wC) * m2[j]);
  }
  u4o.x = uu[0]; u4o.y = uu[1]; u4o.z = uu[2]; u4o.w = uu[3];
  ((ushort4*)(o2 + (size_t)bf * 1024))[t] = u4o;

  float a4[2], m4[2];
  ushort2 u2o;
  #pragma unroll
  for (int j = 0; j < 2; j++) {
    a4[j] = a2[2*j] + a2[2*j+1];
    m4[j] = fmaxf(m2[2*j], m2[2*j+1]);
    unsigned short uv = f2bf_rne(wB * (0.25f * a4[j]) + (1.0f - wB) * m4[j]);
    if (j == 0) u2o.x = uv; else u2o.y = uv;
  }
  ((ushort2*)(o4 + (size_t)bf * 512))[t] = u2o;

  float a8 = a4[0] + a4[1];
  float m8 = fmaxf(m4[0], m4[1]);
  o8[(size_t)bf * 256 + t] = f2bf_rne(wA * (0.125f * a8) + (1.0f - wA) * m8);
}

// ---------------- All weight transposes+cvt in one launch ----------------
// 32x32 tiles; segments: [64|128|256|512|1024|2048] tiles for the 6 matrices
__global__ __launch_bounds__(256) void wt_all_k(
    const float* w10, unsigned short* t10,
    const float* w20, unsigned short* t20,
    const float* w11, unsigned short* t11,
    const float* w21, unsigned short* t21,
    const float* w12, unsigned short* t12,
    const float* w22, unsigned short* t22)
{
  int bx = blockIdx.x;
  const float* W; unsigned short* T; int K, N, loc;
  if      (bx < 64)   { W = w10; T = t10; K = 256;  N = 256;  loc = bx; }
  else if (bx < 192)  { W = w20; T = t20; K = 256;  N = 512;  loc = bx - 64; }
  else if (bx < 448)  { W = w11; T = t11; K = 512;  N = 512;  loc = bx - 192; }
  else if (bx < 960)  { W = w21; T = t21; K = 512;  N = 1024; loc = bx - 448; }
  else if (bx < 1984) { W = w12; T = t12; K = 1024; N = 1024; loc = bx - 960; }
  else                { W = w22; T = t22; K = 1024; N = 2048; loc = bx - 1984; }
  int nx = N >> 5;
  int k0 = (loc / nx) << 5;
  int n0 = (loc % nx) << 5;
  __shared__ float tile[32][33];
  int tx = threadIdx.x & 31, ty = threadIdx.x >> 5;
  #pragma unroll
  for (int i = ty; i < 32; i += 8)
    tile[i][tx] = W[(size_t)(k0 + i) * N + n0 + tx];
  __syncthreads();
  #pragma unroll
  for (int i = ty; i < 32; i += 8)
    T[(size_t)(n0 + i) * K + k0 + tx] = f2bf_rne(tile[tx][i]);
}

// ---------------- bf16 MFMA GEMM, BK=64, XOR-swizzled LDS ----------------
// A: [M][K] bf16 ; Wt: [N][K] bf16. LDS row = 128B (8 x 16B chunks);
// logical chunk c of row m stored at slot c^(m&7)  -> ds_read 2 lanes/bank.
// MODE 0: gelu -> bf16 ; MODE 1: + ColdB(bf16) -> bf16 (in-place ok) ;
// MODE 2: + ColdF(f32) -> f32 (in-place ok)
template<int MODE>
__global__ __launch_bounds__(256) void mgemm_k(
    const unsigned short* __restrict__ A,
    const unsigned short* __restrict__ Wt,
    const float* __restrict__ bias,
    const float* ColdF,
    const unsigned short* ColdB,
    unsigned short* Obf,
    float* Of32,
    int K, int N)
{
  __shared__ v8bf As8[128*8];   // 16 KB
  __shared__ v8bf Bs8[128*8];   // 16 KB
  const int tid  = threadIdx.x;
  const int lane = tid & 63;
  const int w    = tid >> 6;
  const int bm   = blockIdx.y * 128;
  const int bn   = blockIdx.x * 128;
  const int wm   = (w >> 1) * 64;
  const int wn   = (w & 1) * 64;

  v4f acc[4][4];
  #pragma unroll
  for (int i = 0; i < 4; i++)
    #pragma unroll
    for (int j = 0; j < 4; j++)
      acc[i][j] = (v4f){0.f, 0.f, 0.f, 0.f};

  // staging: wave w stages rows [w*32, w*32+32) of A and B tiles, 8 rows/call.
  // lane -> row lane>>3, permuted global 16B chunk (lane&7)^(lane>>3).
  const int lrow = lane >> 3;
  const int lchk = (lane & 7) ^ lrow;
  const unsigned short* ag = A  + (size_t)(bm + w*32 + lrow) * K + lchk * 8;
  const unsigned short* bg = Wt + (size_t)(bn + w*32 + lrow) * K + lchk * 8;
  char* al = (char*)As8 + w*32*128;
  char* bl = (char*)Bs8 + w*32*128;
  const size_t row8 = (size_t)8 * K;

  for (int k0 = 0; k0 < K; k0 += 64) {
    __syncthreads();
    GLDS16(ag + k0,            al);
    GLDS16(ag + row8 + k0,     al + 8*128);
    GLDS16(ag + 2*row8 + k0,   al + 16*128);
    GLDS16(ag + 3*row8 + k0,   al + 24*128);
    GLDS16(bg + k0,            bl);
    GLDS16(bg + row8 + k0,     bl + 8*128);
    GLDS16(bg + 2*row8 + k0,   bl + 16*128);
    GLDS16(bg + 3*row8 + k0,   bl + 24*128);
    __syncthreads();

    #pragma unroll
    for (int u = 0; u < 2; u++) {
      const int cl = (lane >> 4) + u*4;
      const int slot = cl ^ (lane & 7);   // rows below have (m&7)==(lane&7)
      v8bf af[4], bfr[4];
      #pragma unroll
      for (int t = 0; t < 4; t++) {
        af[t]  = As8[(wm + t*16 + (lane & 15))*8 + slot];
        bfr[t] = Bs8[(wn + t*16 + (lane & 15))*8 + slot];
      }
      #pragma unroll
      for (int i = 0; i < 4; i++)
        #pragma unroll
        for (int j = 0; j < 4; j++)
          acc[i][j] = __builtin_amdgcn_mfma_f32_16x16x32_bf16(af[i], bfr[j], acc[i][j], 0, 0, 0);
    }
  }

  // epilogue: C/D layout col=lane&15, row=(lane>>4)*4+reg
  const int col0 = bn + wn + (lane & 15);
  const int row0 = bm + wm + ((lane >> 4) << 2);
  #pragma unroll
  for (int j = 0; j < 4; j++) {
    int c = col0 + j*16;
    float bv = bias[c];
    #pragma unroll
    for (int i = 0; i < 4; i++) {
      #pragma unroll
      for (int r = 0; r < 4; r++) {
        int rr = row0 + i*16 + r;
        size_t idx = (size_t)rr * N + c;
        float t = acc[i][j][r] + bv;
        if (MODE == 0) {
          Obf[idx] = f2bf_rne(gelu_exact(t));
        } else if (MODE == 1) {
          float cold = __bfloat162float(*(const __hip_bfloat16*)&ColdB[idx]);
          Obf[idx] = f2bf_rne(t + cold);
        } else {
          Of32[idx] = t + ColdF[idx];
        }
      }
    }
  }
}

// ---------------- launch ----------------
extern "C" void kernel_launch(void* const* d_in, const int* in_sizes, int n_in,
                              void* d_out, int out_size, void* d_ws, size_t ws_size,
                              hipStream_t stream)
{
  const float* x     = (const float*)d_in[0];
  const float* gamma = (const float*)d_in[1];
  const float* beta  = (const float*)d_in[2];
  float* out = (float*)d_out;
  float* ws  = (float*)d_ws;

  static const int KS[3] = {8, 4, 2};

  // ---- workspace layout (float units) ----
  size_t off = 0;
  float* scl   = ws + off; off += FS_;
  float* shf   = ws + off; off += FS_;
  float* stats = ws + off; off += 3*64*384;
  float* wsel  = ws + off; off += 256;
  unsigned short* sampb[3];
  sampb[0] = (unsigned short*)(ws + off); off += (size_t)M_ * 256 / 2;
  sampb[1] = (unsigned short*)(ws + off); off += (size_t)M_ * 512 / 2;
  sampb[2] = (unsigned short*)(ws + off); off += (size_t)M_ * 1024 / 2;
  unsigned short* hb = (unsigned short*)(ws + off); off += (size_t)M_ * 2048 / 2;
  unsigned short *wt1[3], *wt2[3];
  for (int s = 0; s < 3; s++) {
    int L = S_ / KS[s];
    wt1[s] = (unsigned short*)(ws + off); off += (size_t)L * L / 2;
    wt2[s] = (unsigned short*)(ws + off); off += (size_t)L * 2 * L / 2;
  }

  // ---- weight cvt+transpose: one launch for all 6 matrices ----
  wt_all_k<<<4032, 256, 0, stream>>>(
      (const float*)d_in[3 + 0*8 + 4], wt1[0], (const float*)d_in[3 + 0*8 + 6], wt2[0],
      (const float*)d_in[3 + 1*8 + 4], wt1[1], (const float*)d_in[3 + 1*8 + 6], wt2[1],
      (const float*)d_in[3 + 2*8 + 4], wt1[2], (const float*)d_in[3 + 2*8 + 6], wt2[2]);

  // ---- BN stats -> fused BN-apply + pool-stats -> selectors -> combine ----
  bn_stats_k<<<FS_/4/256, 256, 0, stream>>>(x, gamma, beta, scl, shf);
  bnpool_k<<<M_, 256, 0, stream>>>(x, scl, shf, out, stats);
  selall_k<<<dim3(64, 3), 64, 0, stream>>>(stats,
      (const float*)d_in[3+0], (const float*)d_in[4+0], (const float*)d_in[5+0], (const float*)d_in[6+0],
      (const float*)d_in[3+8], (const float*)d_in[4+8], (const float*)d_in[5+8], (const float*)d_in[6+8],
      (const float*)d_in[3+16], (const float*)d_in[4+16], (const float*)d_in[5+16], (const float*)d_in[6+16],
      wsel);
  combfused_k<<<M_, 256, 0, stream>>>(out, wsel, sampb[0], sampb[1], sampb[2]);

  // ---- GEMM chain (bf16 MFMA) ----
  for (int s = 0; s < 3; s++) {
    int L = S_ / KS[s];
    const float* lb1 = (const float*)d_in[3 + 8*s + 5];
    const float* lb2 = (const float*)d_in[3 + 8*s + 7];
    // h = gelu(samp[s] @ lw1 + lb1) -> bf16
    mgemm_k<0><<<dim3(L/128, M_/128), 256, 0, stream>>>(
        sampb[s], wt1[s], lb1, nullptr, nullptr, hb, nullptr, L, L);
    if (s < 2) {
      // sampb[s+1] += h @ lw2 + lb2   (bf16 in-place)
      mgemm_k<1><<<dim3(2*L/128, M_/128), 256, 0, stream>>>(
          hb, wt2[s], lb2, nullptr, sampb[s+1], sampb[s+1], nullptr, L, 2*L);
    } else {
      // out = xn + h @ lw2 + lb2   (fp32 in-place)
      mgemm_k<2><<<dim3(2*L/128, M_/128), 256, 0, stream>>>(
          hb, wt2[s], lb2, out, nullptr, nullptr, out, L, 2*L);
    }
  }
}

// Round 4
// 371.960 us; speedup vs baseline: 3.4300x; 1.1098x over previous
//
#include <hip/hip_runtime.h>
#include <hip/hip_bf16.h>
#include <math.h>

#define B_ 64
#define F_ 128
#define S_ 2048
#define FS_ (F_*S_)   /* 262144 */
#define M_  (B_*F_)   /* 8192 */
#define EPS_ 1e-5f

typedef __bf16 v8bf __attribute__((ext_vector_type(8)));
typedef float  v16f __attribute__((ext_vector_type(16)));

__device__ __forceinline__ unsigned short f2bf_rne(float f) {
  unsigned int u = __float_as_uint(f);
  u += 0x7FFF + ((u >> 16) & 1);
  return (unsigned short)(u >> 16);
}
__device__ __forceinline__ float b2f(unsigned short u) {
  return __uint_as_float(((unsigned int)u) << 16);
}
__device__ __forceinline__ unsigned int pack2(float a, float b) {
  return (unsigned int)f2bf_rne(a) | ((unsigned int)f2bf_rne(b) << 16);
}

__device__ __forceinline__ float gelu_exact(float x) {
  return 0.5f * x * (1.0f + erff(x * 0.70710678118654752f));
}

// async global->LDS, 16B per lane, lds base wave-uniform, lane lands at +lane*16
#define GLDS16(g, l) __builtin_amdgcn_global_load_lds( \
    (const __attribute__((address_space(1))) unsigned int*)(g), \
    (__attribute__((address_space(3))) unsigned int*)(l), 16, 0, 0)

// ---------------- BatchNorm column stats over batch ----------------
__global__ __launch_bounds__(256) void bn_stats_k(const float* __restrict__ x,
    const float* __restrict__ gamma, const float* __restrict__ beta,
    float* __restrict__ scl, float* __restrict__ shf)
{
  int j4 = blockIdx.x * 256 + threadIdx.x;
  const float4* x4 = (const float4*)x;
  float sum[4] = {0,0,0,0}, sq[4] = {0,0,0,0};
  for (int b = 0; b < B_; b++) {
    float4 v = x4[(size_t)b * (FS_/4) + j4];
    float vv[4] = {v.x, v.y, v.z, v.w};
    #pragma unroll
    for (int i = 0; i < 4; i++) { sum[i] += vv[i]; sq[i] += vv[i]*vv[i]; }
  }
  #pragma unroll
  for (int i = 0; i < 4; i++) {
    int j = j4*4 + i;
    float mu  = sum[i] * (1.0f/B_);
    float var = sq[i] * (1.0f/B_) - mu*mu;
    float rstd = rsqrtf(var + EPS_);
    float g = gamma[j];
    scl[j] = rstd * g;
    shf[j] = beta[j] - mu * rstd * g;
  }
}

// ---------------- Fused BN-apply + hierarchical pool stats; xn -> bf16 ----------------
__global__ __launch_bounds__(256) void bnpool_k(const float* __restrict__ x,
    const float* __restrict__ scl, const float* __restrict__ shf,
    unsigned short* __restrict__ xnb, float* __restrict__ stats)
{
  int bf = blockIdx.x, t = threadIdx.x;
  int b = bf >> 7, f = bf & 127;
  const float4* xp  = (const float4*)(x   + (size_t)bf * S_);
  const float4* scp = (const float4*)(scl + (size_t)f  * S_);
  const float4* shp = (const float4*)(shf + (size_t)f  * S_);

  float xr[8];
  #pragma unroll
  for (int h = 0; h < 2; h++) {
    int i4 = t*2 + h;
    float4 v = xp[i4], sc = scp[i4], sh = shp[i4];
    xr[h*4+0] = fmaf(v.x, sc.x, sh.x);
    xr[h*4+1] = fmaf(v.y, sc.y, sh.y);
    xr[h*4+2] = fmaf(v.z, sc.z, sh.z);
    xr[h*4+3] = fmaf(v.w, sc.w, sh.w);
  }
  uint4 pk;
  pk.x = pack2(xr[0], xr[1]); pk.y = pack2(xr[2], xr[3]);
  pk.z = pack2(xr[4], xr[5]); pk.w = pack2(xr[6], xr[7]);
  ((uint4*)(xnb + (size_t)bf * S_))[t] = pk;

  // level 2 (k=2, L=1024, s=2)
  float a2[4], m2[4];
  float ps2 = 0.f, pq2 = 0.f, pm2 = -INFINITY;
  #pragma unroll
  for (int j = 0; j < 4; j++) {
    a2[j] = xr[2*j] + xr[2*j+1];
    m2[j] = fmaxf(xr[2*j], xr[2*j+1]);
    float pf = 0.5f * (0.5f * a2[j] + m2[j]);
    ps2 += pf; pq2 += pf*pf; pm2 = fmaxf(pm2, pf);
  }
  // level 4 (k=4, L=512, s=1)
  float a4[2], m4[2];
  float ps1 = 0.f, pq1 = 0.f, pm1 = -INFINITY;
  #pragma unroll
  for (int j = 0; j < 2; j++) {
    a4[j] = a2[2*j] + a2[2*j+1];
    m4[j] = fmaxf(m2[2*j], m2[2*j+1]);
    float pf = 0.5f * (0.25f * a4[j] + m4[j]);
    ps1 += pf; pq1 += pf*pf; pm1 = fmaxf(pm1, pf);
  }
  // level 8 (k=8, L=256, s=0)
  float a8 = a4[0] + a4[1];
  float m8 = fmaxf(m4[0], m4[1]);
  float pf8 = 0.5f * (0.125f * a8 + m8);
  float ps0 = pf8, pq0 = pf8*pf8, pm0 = pf8;

  __shared__ float wred[12];
  int lane = t & 63, wid = t >> 6;
  float PS[3] = {ps0, ps1, ps2}, PQ[3] = {pq0, pq1, pq2}, PM[3] = {pm0, pm1, pm2};
  int   LL[3] = {256, 512, 1024};
  #pragma unroll
  for (int s = 0; s < 3; s++) {
    float vs = PS[s], vq = PQ[s], vm = PM[s];
    #pragma unroll
    for (int off = 32; off > 0; off >>= 1) {
      vs += __shfl_down(vs, off);
      vq += __shfl_down(vq, off);
      vm = fmaxf(vm, __shfl_down(vm, off));
    }
    if (lane == 0) { wred[wid*3+0] = vs; wred[wid*3+1] = vq; wred[wid*3+2] = vm; }
    __syncthreads();
    if (t == 0) {
      float S = 0.f, Q = 0.f, Mx = -INFINITY;
      #pragma unroll
      for (int i = 0; i < 4; i++) {
        S += wred[i*3+0]; Q += wred[i*3+1]; Mx = fmaxf(Mx, wred[i*3+2]);
      }
      float L = (float)LL[s];
      float mean = S / L;
      float var  = (Q - S*S/L) / (L - 1.0f);
      float* base = stats + s*(64*384) + b*384;
      base[f]       = mean;
      base[128 + f] = sqrtf(fmaxf(var, 0.0f));
      base[256 + f] = Mx;
    }
    __syncthreads();
  }
}

// ---------------- All three selector MLPs in one launch ----------------
__global__ __launch_bounds__(64) void selall_k(const float* __restrict__ stats,
    const float* w1_0, const float* b1_0, const float* w2_0, const float* b2_0,
    const float* w1_1, const float* b1_1, const float* w2_1, const float* b2_1,
    const float* w1_2, const float* b1_2, const float* w2_2, const float* b2_2,
    float* __restrict__ wsel)
{
  int s = blockIdx.y, b = blockIdx.x, j = threadIdx.x;
  const float *w1, *b1, *w2, *b2;
  if      (s == 0) { w1 = w1_0; b1 = b1_0; w2 = w2_0; b2 = b2_0; }
  else if (s == 1) { w1 = w1_1; b1 = b1_1; w2 = w2_1; b2 = b2_1; }
  else             { w1 = w1_2; b1 = b1_2; w2 = w2_2; b2 = b2_2; }
  const float* st = stats + s*(64*384) + b*384;
  float acc = b1[j];
  for (int i = 0; i < 384; i++) acc = fmaf(st[i], w1[i*64 + j], acc);
  float h = fmaxf(acc, 0.0f);
  float v = h * w2[j];
  for (int off = 32; off > 0; off >>= 1) v += __shfl_down(v, off);
  if (j == 0) wsel[s*64 + b] = 1.0f / (1.0f + expf(-(v + b2[0])));
}

// ---------------- Fused pool-recompute + combine (bf16 in) -> bf16 A matrices ----------------
__global__ __launch_bounds__(256) void combfused_k(const unsigned short* __restrict__ xnb,
    const float* __restrict__ wsel,
    unsigned short* __restrict__ o8, unsigned short* __restrict__ o4,
    unsigned short* __restrict__ o2)
{
  int bf = blockIdx.x, t = threadIdx.x, b = bf >> 7;
  float wA = wsel[b];            // k=8 (s=0)
  float wB = wsel[64 + b];       // k=4 (s=1)
  float wC = wsel[128 + b];      // k=2 (s=2)
  uint4 pk = ((const uint4*)(xnb + (size_t)bf * S_))[t];
  unsigned int pw[4] = {pk.x, pk.y, pk.z, pk.w};
  float xr[8];
  #pragma unroll
  for (int h = 0; h < 4; h++) {
    xr[2*h]   = b2f((unsigned short)(pw[h] & 0xFFFF));
    xr[2*h+1] = b2f((unsigned short)(pw[h] >> 16));
  }
  float a2[4], m2[4];
  ushort4 u4o;
  unsigned short uu[4];
  #pragma unroll
  for (int j = 0; j < 4; j++) {
    a2[j] = xr[2*j] + xr[2*j+1];
    m2[j] = fmaxf(xr[2*j], xr[2*j+1]);
    uu[j] = f2bf_rne(wC * (0.5f * a2[j]) + (1.0f - wC) * m2[j]);
  }
  u4o.x = uu[0]; u4o.y = uu[1]; u4o.z = uu[2]; u4o.w = uu[3];
  ((ushort4*)(o2 + (size_t)bf * 1024))[t] = u4o;

  float a4[2], m4[2];
  ushort2 u2o;
  #pragma unroll
  for (int j = 0; j < 2; j++) {
    a4[j] = a2[2*j] + a2[2*j+1];
    m4[j] = fmaxf(m2[2*j], m2[2*j+1]);
    unsigned short uv = f2bf_rne(wB * (0.25f * a4[j]) + (1.0f - wB) * m4[j]);
    if (j == 0) u2o.x = uv; else u2o.y = uv;
  }
  ((ushort2*)(o4 + (size_t)bf * 512))[t] = u2o;

  float a8 = a4[0] + a4[1];
  float m8 = fmaxf(m4[0], m4[1]);
  o8[(size_t)bf * 256 + t] = f2bf_rne(wA * (0.125f * a8) + (1.0f - wA) * m8);
}

// ---------------- All weight transposes+cvt in one launch ----------------
__global__ __launch_bounds__(256) void wt_all_k(
    const float* w10, unsigned short* t10,
    const float* w20, unsigned short* t20,
    const float* w11, unsigned short* t11,
    const float* w21, unsigned short* t21,
    const float* w12, unsigned short* t12,
    const float* w22, unsigned short* t22)
{
  int bx = blockIdx.x;
  const float* W; unsigned short* T; int K, N, loc;
  if      (bx < 64)   { W = w10; T = t10; K = 256;  N = 256;  loc = bx; }
  else if (bx < 192)  { W = w20; T = t20; K = 256;  N = 512;  loc = bx - 64; }
  else if (bx < 448)  { W = w11; T = t11; K = 512;  N = 512;  loc = bx - 192; }
  else if (bx < 960)  { W = w21; T = t21; K = 512;  N = 1024; loc = bx - 448; }
  else if (bx < 1984) { W = w12; T = t12; K = 1024; N = 1024; loc = bx - 960; }
  else                { W = w22; T = t22; K = 1024; N = 2048; loc = bx - 1984; }
  int nx = N >> 5;
  int k0 = (loc / nx) << 5;
  int n0 = (loc % nx) << 5;
  __shared__ float tile[32][33];
  int tx = threadIdx.x & 31, ty = threadIdx.x >> 5;
  #pragma unroll
  for (int i = ty; i < 32; i += 8)
    tile[i][tx] = W[(size_t)(k0 + i) * N + n0 + tx];
  __syncthreads();
  #pragma unroll
  for (int i = ty; i < 32; i += 8)
    T[(size_t)(n0 + i) * K + k0 + tx] = f2bf_rne(tile[tx][i]);
}

// ---------------- bf16 MFMA GEMM, 32x32x16 shape, BK=64, XOR-swizzled LDS ----------------
// A: [M][K] bf16 ; Wt: [N][K] bf16. Block tile TM x 128, 4 waves.
// TM=128: wave tile 64x64 (2x2 of 32x32). TM=64: wave tile 32x64 (1x2).
// LDS row = 128B (8 x 16B chunks); logical chunk c of row m at slot c^(m&7).
// 32x32x16 frags: A row = lane&31, k-chunk = lane>>5 (8 bf16); B same on Wt rows.
// C/D: col = lane&31, row = (reg&3) + 8*(reg>>2) + 4*(lane>>5)   [m74/m101]
// MODE 0: gelu -> bf16 ; MODE 1: + Cold(bf16) -> bf16 ; MODE 2: + Cold(bf16) -> f32
template<int MODE, int TM>
__global__ __launch_bounds__(256) void mgemm_k(
    const unsigned short* __restrict__ A,
    const unsigned short* __restrict__ Wt,
    const float* __restrict__ bias,
    const unsigned short* Cold,
    unsigned short* Obf,
    float* Of32,
    int K, int N)
{
  constexpr int MI = TM / 64;          // m-subtiles per wave (2 or 1)
  constexpr int RA = TM / 4;           // A rows staged per wave (32 or 16)
  __shared__ v8bf As8[TM * 8];
  __shared__ v8bf Bs8[128 * 8];
  const int tid  = threadIdx.x;
  const int lane = tid & 63;
  const int w    = tid >> 6;
  const int bm   = blockIdx.y * TM;
  const int bn   = blockIdx.x * 128;
  const int wm   = (w >> 1) * (TM / 2);   // 0/64 or 0/32
  const int wn   = (w & 1) * 64;

  v16f acc[MI][2];
  #pragma unroll
  for (int i = 0; i < MI; i++)
    #pragma unroll
    for (int j = 0; j < 2; j++)
      #pragma unroll
      for (int r = 0; r < 16; r++) acc[i][j][r] = 0.f;

  const int lrow = lane >> 3;                  // 0..7
  const int lchk = (lane & 7) ^ lrow;          // permuted global 16B chunk
  const unsigned short* ag = A  + (size_t)(bm + w*RA + lrow) * K + lchk * 8;
  const unsigned short* bg = Wt + (size_t)(bn + w*32 + lrow) * K + lchk * 8;
  char* al = (char*)As8 + w*RA*128;
  char* bl = (char*)Bs8 + w*32*128;
  const size_t row8 = (size_t)8 * K;

  for (int k0 = 0; k0 < K; k0 += 64) {
    __syncthreads();
    #pragma unroll
    for (int q = 0; q < RA/8; q++)
      GLDS16(ag + q*row8 + k0, al + q*8*128);
    #pragma unroll
    for (int q = 0; q < 4; q++)
      GLDS16(bg + q*row8 + k0, bl + q*8*128);
    __syncthreads();

    #pragma unroll
    for (int s = 0; s < 4; s++) {
      const int c = 2*s + (lane >> 5);
      const int slot = c ^ (lane & 7);   // rows below have (m&7)==(lane&7)
      v8bf af[MI], bfr[2];
      #pragma unroll
      for (int i = 0; i < MI; i++)
        af[i] = As8[(wm + i*32 + (lane & 31))*8 + slot];
      #pragma unroll
      for (int j = 0; j < 2; j++)
        bfr[j] = Bs8[(wn + j*32 + (lane & 31))*8 + slot];
      #pragma unroll
      for (int i = 0; i < MI; i++)
        #pragma unroll
        for (int j = 0; j < 2; j++)
          acc[i][j] = __builtin_amdgcn_mfma_f32_32x32x16_bf16(af[i], bfr[j], acc[i][j], 0, 0, 0);
    }
  }

  const int col0 = bn + wn + (lane & 31);
  const int rb0  = bm + wm + ((lane >> 5) << 2);
  #pragma unroll
  for (int j = 0; j < 2; j++) {
    int c = col0 + j*32;
    float bv = bias[c];
    #pragma unroll
    for (int i = 0; i < MI; i++) {
      #pragma unroll
      for (int r = 0; r < 16; r++) {
        int rr = rb0 + i*32 + (r & 3) + ((r >> 2) << 3);
        size_t idx = (size_t)rr * N + c;
        float t = acc[i][j][r] + bv;
        if (MODE == 0) {
          Obf[idx] = f2bf_rne(gelu_exact(t));
        } else if (MODE == 1) {
          Obf[idx] = f2bf_rne(t + b2f(Cold[idx]));
        } else {
          Of32[idx] = t + b2f(Cold[idx]);
        }
      }
    }
  }
}

// ---------------- launch ----------------
extern "C" void kernel_launch(void* const* d_in, const int* in_sizes, int n_in,
                              void* d_out, int out_size, void* d_ws, size_t ws_size,
                              hipStream_t stream)
{
  const float* x     = (const float*)d_in[0];
  const float* gamma = (const float*)d_in[1];
  const float* beta  = (const float*)d_in[2];
  float* out = (float*)d_out;
  float* ws  = (float*)d_ws;

  static const int KS[3] = {8, 4, 2};

  // ---- workspace layout (float units) ----
  size_t off = 0;
  float* scl   = ws + off; off += FS_;
  float* shf   = ws + off; off += FS_;
  float* stats = ws + off; off += 3*64*384;
  float* wsel  = ws + off; off += 256;
  unsigned short* xnb = (unsigned short*)(ws + off); off += (size_t)M_ * S_ / 2;
  unsigned short* sampb[3];
  sampb[0] = (unsigned short*)(ws + off); off += (size_t)M_ * 256 / 2;
  sampb[1] = (unsigned short*)(ws + off); off += (size_t)M_ * 512 / 2;
  sampb[2] = (unsigned short*)(ws + off); off += (size_t)M_ * 1024 / 2;
  unsigned short* hb = (unsigned short*)(ws + off); off += (size_t)M_ * 2048 / 2;
  unsigned short *wt1[3], *wt2[3];
  for (int s = 0; s < 3; s++) {
    int L = S_ / KS[s];
    wt1[s] = (unsigned short*)(ws + off); off += (size_t)L * L / 2;
    wt2[s] = (unsigned short*)(ws + off); off += (size_t)L * 2 * L / 2;
  }

  // ---- weight cvt+transpose ----
  wt_all_k<<<4032, 256, 0, stream>>>(
      (const float*)d_in[3 + 0*8 + 4], wt1[0], (const float*)d_in[3 + 0*8 + 6], wt2[0],
      (const float*)d_in[3 + 1*8 + 4], wt1[1], (const float*)d_in[3 + 1*8 + 6], wt2[1],
      (const float*)d_in[3 + 2*8 + 4], wt1[2], (const float*)d_in[3 + 2*8 + 6], wt2[2]);

  // ---- BN stats -> fused BN-apply(bf16 xn) + pool-stats -> selectors -> combine ----
  bn_stats_k<<<FS_/4/256, 256, 0, stream>>>(x, gamma, beta, scl, shf);
  bnpool_k<<<M_, 256, 0, stream>>>(x, scl, shf, xnb, stats);
  selall_k<<<dim3(64, 3), 64, 0, stream>>>(stats,
      (const float*)d_in[3+0], (const float*)d_in[4+0], (const float*)d_in[5+0], (const float*)d_in[6+0],
      (const float*)d_in[3+8], (const float*)d_in[4+8], (const float*)d_in[5+8], (const float*)d_in[6+8],
      (const float*)d_in[3+16], (const float*)d_in[4+16], (const float*)d_in[5+16], (const float*)d_in[6+16],
      wsel);
  combfused_k<<<M_, 256, 0, stream>>>(xnb, wsel, sampb[0], sampb[1], sampb[2]);

  // ---- GEMM chain (bf16 MFMA 32x32x16) ----
  // s=0: L=256
  mgemm_k<0,64><<<dim3(2, 128), 256, 0, stream>>>(
      sampb[0], wt1[0], (const float*)d_in[3+0*8+5], nullptr, hb, nullptr, 256, 256);
  mgemm_k<1,64><<<dim3(4, 128), 256, 0, stream>>>(
      hb, wt2[0], (const float*)d_in[3+0*8+7], sampb[1], sampb[1], nullptr, 256, 512);
  // s=1: L=512
  mgemm_k<0,64><<<dim3(4, 128), 256, 0, stream>>>(
      sampb[1], wt1[1], (const float*)d_in[3+1*8+5], nullptr, hb, nullptr, 512, 512);
  mgemm_k<1,64><<<dim3(8, 128), 256, 0, stream>>>(
      hb, wt2[1], (const float*)d_in[3+1*8+7], sampb[2], sampb[2], nullptr, 512, 1024);
  // s=2: L=1024
  mgemm_k<0,64><<<dim3(8, 128), 256, 0, stream>>>(
      sampb[2], wt1[2], (const float*)d_in[3+2*8+5], nullptr, hb, nullptr, 1024, 1024);
  mgemm_k<2,128><<<dim3(16, 64), 256, 0, stream>>>(
      hb, wt2[2], (const float*)d_in[3+2*8+7], xnb, nullptr, out, 1024, 2048);
}